// Round 5
// baseline (186.699 us; speedup 1.0000x reference)
//
#include <hip/hip_runtime.h>
#include <hip/hip_cooperative_groups.h>

namespace cg = cooperative_groups;

// Problem constants (from reference setup_inputs)
constexpr int B_  = 8;
constexpr int T_  = 16;
constexpr int C_  = 256;
constexpr int HW_ = 784;   // 28*28
constexpr int CO_ = 64;    // C/4
constexpr int K_  = 7;     // KSZ
constexpr int U2_ = 32;    // 2*T
constexpr int NCH = B_ * C_;    // 2048 channels
constexpr int NTY = B_ * CO_;   // 512 (b,o) units

typedef float floatx4 __attribute__((ext_vector_type(4)));

__device__ __forceinline__ float rfl(float v) {
    return __int_as_float(__builtin_amdgcn_readfirstlane(__float_as_int(v)));
}

// ---------------------------------------------------------------------------
// Fused cooperative kernel.
//  Epoch 1: pooled[b,c,t] = mean_hw x[b,t,c,:,:]            (reads x, HBM)
//  Epoch 2: ty[b,o,t] = tanh(conv1d(pooled; Wl1))           (tiny)
//  Epoch 3: per channel: kw=softmax(W2.tanh(W1.pooled)), loc=sigmoid(Wl2.ty);
//           out[b,t,c,:] = sum_d kw[d] * loc[t+d] * x[b,t+d,c,:]
//           (re-reads x — L3-warm from epoch 1 — writes out nontemporally)
// ---------------------------------------------------------------------------
__global__ __launch_bounds__(256, 4)
void tam_fused(const float* __restrict__ x,  const float* __restrict__ W1,
               const float* __restrict__ W2, const float* __restrict__ Wl1,
               const float* __restrict__ Wl2, float* __restrict__ out,
               float* __restrict__ pooled,    float* __restrict__ ty) {
    cg::grid_group grid = cg::this_grid();
    const int g   = blockIdx.x;
    const int G   = gridDim.x;
    const int tid = threadIdx.x;
    const int wave = tid >> 6, lane = tid & 63;
    const size_t ts = (size_t)C_ * HW_;   // t-stride in floats

    __shared__ float pld[T_ * 257];   // epoch-2 staging (16.4 KB)
    __shared__ float pool_s[T_];
    __shared__ float g_s[U2_];
    __shared__ float s_s[8];
    __shared__ float kw_s[8];
    __shared__ float loc_s[T_];

    // ---------------- Epoch 1: pool ----------------
    for (int bc = g; bc < NCH; bc += G) {
        int b = bc >> 8, c = bc & 255;
        const float* xc = x + ((size_t)(b * T_) * C_ + c) * HW_;
#pragma unroll
        for (int j = 0; j < 4; ++j) {
            int t = wave * 4 + j;
            const floatx4* p4 = (const floatx4*)(xc + (size_t)t * ts);
            float s = 0.f;
            for (int col = lane; col < 196; col += 64) {
                floatx4 v = p4[col];
                s += (v.x + v.y) + (v.z + v.w);
            }
#pragma unroll
            for (int m = 32; m >= 1; m >>= 1) s += __shfl_xor(s, m, 64);
            if (lane == 0) pooled[(size_t)bc * T_ + t] = s * (1.0f / 784.0f);
        }
    }
    grid.sync();

    // ---------------- Epoch 2: ty ----------------
    for (int u = g; u < NTY; u += G) {
        int b = u / CO_, o = u % CO_;
        for (int idx = tid; idx < C_ * T_; idx += 256) {
            int i = idx >> 4, tt = idx & 15;
            pld[tt * 257 + i] = pooled[((size_t)b * C_ + i) * T_ + tt];
        }
        __syncthreads();
        int t = tid >> 4, q = tid & 15;
        const float* wrow = Wl1 + (size_t)o * (C_ * K_);
        float acc = 0.f;
        for (int jm = 0; jm < 16; ++jm) {
            int i = jm * 16 + q;
            const float* wp = wrow + i * K_;
#pragma unroll
            for (int k = 0; k < K_; ++k) {
                int tt = t + k - 3;
                if (tt >= 0 && tt < T_) acc += wp[k] * pld[tt * 257 + i];
            }
        }
        acc += __shfl_xor(acc, 1, 64);
        acc += __shfl_xor(acc, 2, 64);
        acc += __shfl_xor(acc, 4, 64);
        acc += __shfl_xor(acc, 8, 64);
        if (q == 0) ty[(size_t)u * T_ + t] = tanhf(acc);
        __syncthreads();
    }
    grid.sync();

    // ---------------- Epoch 3: coefficients + stream, per channel ----------
    for (int bc = g; bc < NCH; bc += G) {
        int b = bc >> 8, c = bc & 255;

        // loc[t] = sigmoid(Wl2[c,:] . ty[b,:,t]) — 16 t-groups x 16 splitters
        {
            int t = tid >> 4, q = tid & 15;
            float acc = 0.f;
#pragma unroll
            for (int jj = 0; jj < 4; ++jj) {
                int o = q + jj * 16;
                acc += Wl2[(size_t)c * CO_ + o] * ty[((size_t)b * CO_ + o) * T_ + t];
            }
            acc += __shfl_xor(acc, 1, 64);
            acc += __shfl_xor(acc, 2, 64);
            acc += __shfl_xor(acc, 4, 64);
            acc += __shfl_xor(acc, 8, 64);
            if (q == 0) loc_s[t] = 1.0f / (1.0f + __expf(-acc));
        }
        if (tid < T_) pool_s[tid] = pooled[(size_t)bc * T_ + tid];
        __syncthreads();
        if (tid < U2_) {
            float acc = 0.f;
#pragma unroll
            for (int t2 = 0; t2 < T_; ++t2) acc += pool_s[t2] * W1[tid * T_ + t2];
            g_s[tid] = tanhf(acc);
        }
        __syncthreads();
        if (tid < K_) {
            float acc = 0.f;
#pragma unroll
            for (int u2 = 0; u2 < U2_; ++u2) acc += g_s[u2] * W2[tid * U2_ + u2];
            s_s[tid] = acc;
        }
        __syncthreads();
        if (tid == 0) {
            float m = s_s[0];
#pragma unroll
            for (int k = 1; k < K_; ++k) m = fmaxf(m, s_s[k]);
            float e[K_], sum = 0.f;
#pragma unroll
            for (int k = 0; k < K_; ++k) { e[k] = __expf(s_s[k] - m); sum += e[k]; }
            float inv = 1.0f / sum;
#pragma unroll
            for (int k = 0; k < K_; ++k) kw_s[k] = e[k] * inv;
        }
        __syncthreads();

        // uniform coefficients -> SGPR
        float kw[K_], lc[T_];
#pragma unroll
        for (int k = 0; k < K_; ++k) kw[k] = rfl(kw_s[k]);
#pragma unroll
        for (int t = 0; t < T_; ++t) lc[t] = rfl(loc_s[t]);
        __syncthreads();   // all lanes captured coeffs before next iter's LDS writes

        // stream: col-per-thread, two t-halves with 11-deep float4 window
        if (tid < 196) {
            const size_t chan = ((size_t)(b * T_) * C_ + c) * HW_ + (size_t)tid * 4;
            const float* xb = x + chan;
            float*       ob = out + chan;

            floatx4 w[11];
#pragma unroll
            for (int tp = 0; tp < 11; ++tp)
                w[tp] = *(const floatx4*)(xb + (size_t)tp * ts) * lc[tp];
#pragma unroll
            for (int t = 0; t < 8; ++t) {
                floatx4 acc = {0.f, 0.f, 0.f, 0.f};
#pragma unroll
                for (int d = -3; d <= 3; ++d) {
                    int tp = t + d;
                    if (tp >= 0 && tp <= 10) acc += kw[d + 3] * w[tp];
                }
                __builtin_nontemporal_store(acc, (floatx4*)(ob + (size_t)t * ts));
            }

            floatx4 w2[11];
#pragma unroll
            for (int j = 0; j < 6; ++j) w2[j] = w[5 + j];
#pragma unroll
            for (int tp = 11; tp < 16; ++tp)
                w2[tp - 5] = *(const floatx4*)(xb + (size_t)tp * ts) * lc[tp];
#pragma unroll
            for (int t = 8; t < 16; ++t) {
                floatx4 acc = {0.f, 0.f, 0.f, 0.f};
#pragma unroll
                for (int d = -3; d <= 3; ++d) {
                    int tp = t + d;                 // in [5,18]
                    if (tp <= 15) acc += kw[d + 3] * w2[tp - 5];
                }
                __builtin_nontemporal_store(acc, (floatx4*)(ob + (size_t)t * ts));
            }
        }
    }
}

extern "C" void kernel_launch(void* const* d_in, const int* in_sizes, int n_in,
                              void* d_out, int out_size, void* d_ws, size_t ws_size,
                              hipStream_t stream) {
    const float* x   = (const float*)d_in[0];
    const float* W1  = (const float*)d_in[1];
    const float* W2  = (const float*)d_in[2];
    const float* Wl1 = (const float*)d_in[3];
    const float* Wl2 = (const float*)d_in[4];
    float* out = (float*)d_out;

    float* pooled = (float*)d_ws;                 // NCH*T  = 32768 floats
    float* ty     = pooled + NCH * T_;            // NTY*T  =  8192 floats

    // co-residency-safe grid (grid-stride phases tolerate any grid >= 1)
    int blocksPerCU = 0;
    hipOccupancyMaxActiveBlocksPerMultiprocessor(&blocksPerCU,
        (const void*)tam_fused, 256, 0);
    if (blocksPerCU < 1) blocksPerCU = 1;
    int grid = blocksPerCU * 256;                 // 256 CUs on MI355X
    if (grid > 1024) grid = 1024;

    void* args[] = { (void*)&x, (void*)&W1, (void*)&W2, (void*)&Wl1,
                     (void*)&Wl2, (void*)&out, (void*)&pooled, (void*)&ty };
    hipLaunchCooperativeKernel((const void*)tam_fused, dim3(grid), dim3(256),
                               args, 0, stream);
}

// Round 6
// 74.259 us; speedup vs baseline: 2.5142x; 2.5142x over previous
//
#include <hip/hip_runtime.h>

// Problem constants (from reference setup_inputs)
constexpr int B_  = 8;
constexpr int T_  = 16;
constexpr int C_  = 256;
constexpr int HW_ = 784;   // 28*28
constexpr int CO_ = 64;    // C/4
constexpr int K_  = 7;     // KSZ
constexpr int U2_ = 32;    // 2*T

typedef float    floatx4 __attribute__((ext_vector_type(4)));
typedef _Float16 half4   __attribute__((ext_vector_type(4)));

__device__ __forceinline__ float rfl(float v) {
    return __int_as_float(__builtin_amdgcn_readfirstlane(__float_as_int(v)));
}

// ---------------------------------------------------------------------------
// Kernel 1: pool (+ optional fp16 transpose-copy).
//   pooled[b,c,t] = mean_hw x[b,t,c,:,:]
//   x16[b,c,t,hw] = (fp16) x[b,t,c,hw]   -- channel-major, 25KB/channel
// One wave per (b,t,c) slice. 4 waves per block.
// ---------------------------------------------------------------------------
__global__ __launch_bounds__(256) void pool_cvt_kernel(const float* __restrict__ x,
                                                       float* __restrict__ pooled,
                                                       _Float16* __restrict__ x16) {
    int bid  = blockIdx.x;          // (b*T + t)*(C/4) + cg
    int cg   = bid & 63;
    int bt   = bid >> 6;            // b*T + t
    int t    = bt & 15;
    int b    = bt >> 4;
    int wave = threadIdx.x >> 6;
    int lane = threadIdx.x & 63;
    int c    = cg * 4 + wave;

    const floatx4* p4 = (const floatx4*)(x + ((size_t)bt * C_ + c) * HW_);
    half4* d4 = x16 ? (half4*)(x16 + ((size_t)(b * C_ + c) * T_ + t) * HW_) : nullptr;

    float s = 0.f;
    for (int j = lane; j < 196; j += 64) {   // 196 float4 = 784 floats
        floatx4 v = p4[j];
        s += (v.x + v.y) + (v.z + v.w);
        if (d4) d4[j] = __builtin_convertvector(v, half4);
    }
#pragma unroll
    for (int m = 32; m >= 1; m >>= 1) s += __shfl_xor(s, m, 64);
    if (lane == 0) pooled[((size_t)b * C_ + c) * T_ + t] = s * (1.0f / 784.0f);
}

// ---------------------------------------------------------------------------
// Kernel 2: L-branch conv1d (C -> C/4, k=7, pad=3) + tanh
// ---------------------------------------------------------------------------
__global__ __launch_bounds__(256) void ty_kernel(const float* __restrict__ pooled,
                                                 const float* __restrict__ Wl1,
                                                 float* __restrict__ ty) {
    int b = blockIdx.x / CO_;
    int o = blockIdx.x % CO_;
    __shared__ float pld[T_ * 257];

    int tid = threadIdx.x;
    for (int idx = tid; idx < C_ * T_; idx += 256) {
        int i  = idx >> 4;
        int tt = idx & 15;
        pld[tt * 257 + i] = pooled[((size_t)b * C_ + i) * T_ + tt];
    }
    __syncthreads();

    int t = tid >> 4;
    int q = tid & 15;
    const float* wrow = Wl1 + (size_t)o * (C_ * K_);
    float acc = 0.f;
    for (int j = 0; j < 16; ++j) {
        int i = j * 16 + q;
        const float* wp = wrow + i * K_;
#pragma unroll
        for (int k = 0; k < K_; ++k) {
            int tt = t + k - 3;
            if (tt >= 0 && tt < T_) acc += wp[k] * pld[tt * 257 + i];
        }
    }
    acc += __shfl_xor(acc, 1, 64);
    acc += __shfl_xor(acc, 2, 64);
    acc += __shfl_xor(acc, 4, 64);
    acc += __shfl_xor(acc, 8, 64);
    if (q == 0) ty[((size_t)b * CO_ + o) * T_ + t] = tanhf(acc);
}

// ---------------------------------------------------------------------------
// Kernel 3: per-(b,c) coefficients -> P[bc][32]:
//   P[0..6] = kw (softmax), P[8..23] = loc (sigmoid)
// ---------------------------------------------------------------------------
__global__ __launch_bounds__(64) void abuild_kernel(const float* __restrict__ pooled,
                                                    const float* __restrict__ ty,
                                                    const float* __restrict__ W1,
                                                    const float* __restrict__ W2,
                                                    const float* __restrict__ Wl2,
                                                    float* __restrict__ P) {
    int bc = blockIdx.x;
    int b  = bc >> 8;
    int c  = bc & 255;
    int lane = threadIdx.x;

    __shared__ float g_s[U2_];
    __shared__ float s_s[K_];
    __shared__ float loc_s[T_];
    __shared__ float kw_s[8];

    {
        int t = lane >> 2, q = lane & 3;
        float acc = 0.f;
#pragma unroll
        for (int jj = 0; jj < 16; ++jj) {
            int i = q * 16 + jj;
            acc += Wl2[(size_t)c * CO_ + i] * ty[((size_t)b * CO_ + i) * T_ + t];
        }
        acc += __shfl_xor(acc, 1, 64);
        acc += __shfl_xor(acc, 2, 64);
        if (q == 0) loc_s[t] = 1.0f / (1.0f + __expf(-acc));
    }
    if (lane < U2_) {
        float acc = 0.f;
#pragma unroll
        for (int t2 = 0; t2 < T_; ++t2)
            acc += pooled[((size_t)b * C_ + c) * T_ + t2] * W1[lane * T_ + t2];
        g_s[lane] = tanhf(acc);
    }
    __syncthreads();
    if (lane < K_) {
        float acc = 0.f;
#pragma unroll
        for (int u = 0; u < U2_; ++u) acc += g_s[u] * W2[lane * U2_ + u];
        s_s[lane] = acc;
    }
    __syncthreads();
    if (lane == 0) {
        float m = s_s[0];
#pragma unroll
        for (int k = 1; k < K_; ++k) m = fmaxf(m, s_s[k]);
        float e[K_], sum = 0.f;
#pragma unroll
        for (int k = 0; k < K_; ++k) { e[k] = __expf(s_s[k] - m); sum += e[k]; }
        float inv = 1.0f / sum;
#pragma unroll
        for (int k = 0; k < K_; ++k) kw_s[k] = e[k] * inv;
        kw_s[7] = 0.f;
    }
    __syncthreads();
    float* row = P + (size_t)bc * 32;
    if (lane < 8)                 row[lane] = kw_s[lane];
    if (lane >= 8 && lane < 24)   row[lane] = loc_s[lane - 8];
}

// ---------------------------------------------------------------------------
// Kernel 4a: stream from fp16 transposed copy (channel = 25KB contiguous).
// One block per (b,c); thread col<196 owns 4 hw columns.
// ---------------------------------------------------------------------------
__global__ __launch_bounds__(256) void stream16_kernel(const _Float16* __restrict__ x16,
                                                       const float* __restrict__ P,
                                                       float* __restrict__ out) {
    int bc = blockIdx.x;         // block-uniform
    int b  = bc >> 8;
    int c  = bc & 255;
    int col = threadIdx.x;

    const float* row = P + (size_t)bc * 32;
    float kw[K_], lc[T_];
#pragma unroll
    for (int k = 0; k < K_; ++k) kw[k] = rfl(row[k]);
#pragma unroll
    for (int t = 0; t < T_; ++t) lc[t] = rfl(row[8 + t]);

    if (col >= 196) return;

    const _Float16* xb = x16 + (size_t)bc * T_ * HW_ + (size_t)col * 4;  // slice stride 784
    float* ob = out + ((size_t)(b * T_) * C_ + c) * HW_ + (size_t)col * 4;
    const size_t ts = (size_t)C_ * HW_;   // out t-stride (floats)

    // first half: out[0..7] needs y[0..10]
    floatx4 w[11];
#pragma unroll
    for (int tp = 0; tp < 11; ++tp) {
        half4 h = *(const half4*)(xb + tp * HW_);
        w[tp] = __builtin_convertvector(h, floatx4) * lc[tp];
    }
#pragma unroll
    for (int t = 0; t < 8; ++t) {
        floatx4 acc = {0.f, 0.f, 0.f, 0.f};
#pragma unroll
        for (int d = -3; d <= 3; ++d) {
            int tp = t + d;
            if (tp >= 0 && tp <= 10) acc += kw[d + 3] * w[tp];
        }
        __builtin_nontemporal_store(acc, (floatx4*)(ob + (size_t)t * ts));
    }

    // second half: out[8..15] needs y[5..15]
    floatx4 w2[11];
#pragma unroll
    for (int j = 0; j < 6; ++j) w2[j] = w[5 + j];
#pragma unroll
    for (int tp = 11; tp < 16; ++tp) {
        half4 h = *(const half4*)(xb + tp * HW_);
        w2[tp - 5] = __builtin_convertvector(h, floatx4) * lc[tp];
    }
#pragma unroll
    for (int t = 8; t < 16; ++t) {
        floatx4 acc = {0.f, 0.f, 0.f, 0.f};
#pragma unroll
        for (int d = -3; d <= 3; ++d) {
            int tp = t + d;
            if (tp <= 15) acc += kw[d + 3] * w2[tp - 5];
        }
        __builtin_nontemporal_store(acc, (floatx4*)(ob + (size_t)t * ts));
    }
}

// ---------------------------------------------------------------------------
// Kernel 4b: fallback f32 stream (reads x directly) if ws can't hold x16.
// ---------------------------------------------------------------------------
__global__ __launch_bounds__(256) void stream_kernel(const float* __restrict__ x,
                                                     const float* __restrict__ P,
                                                     float* __restrict__ out) {
    int bc = blockIdx.x;
    int b  = bc >> 8;
    int c  = bc & 255;
    int col = threadIdx.x;

    const float* row = P + (size_t)bc * 32;
    float kw[K_], lc[T_];
#pragma unroll
    for (int k = 0; k < K_; ++k) kw[k] = rfl(row[k]);
#pragma unroll
    for (int t = 0; t < T_; ++t) lc[t] = rfl(row[8 + t]);

    if (col >= 196) return;

    const size_t chan = ((size_t)(b * T_) * C_ + c) * HW_ + (size_t)col * 4;
    const float* xb = x + chan;
    float*       ob = out + chan;
    const size_t ts = (size_t)C_ * HW_;

    floatx4 w[11];
#pragma unroll
    for (int tp = 0; tp < 11; ++tp)
        w[tp] = *(const floatx4*)(xb + (size_t)tp * ts) * lc[tp];
#pragma unroll
    for (int t = 0; t < 8; ++t) {
        floatx4 acc = {0.f, 0.f, 0.f, 0.f};
#pragma unroll
        for (int d = -3; d <= 3; ++d) {
            int tp = t + d;
            if (tp >= 0 && tp <= 10) acc += kw[d + 3] * w[tp];
        }
        __builtin_nontemporal_store(acc, (floatx4*)(ob + (size_t)t * ts));
    }
    floatx4 w2[11];
#pragma unroll
    for (int j = 0; j < 6; ++j) w2[j] = w[5 + j];
#pragma unroll
    for (int tp = 11; tp < 16; ++tp)
        w2[tp - 5] = *(const floatx4*)(xb + (size_t)tp * ts) * lc[tp];
#pragma unroll
    for (int t = 8; t < 16; ++t) {
        floatx4 acc = {0.f, 0.f, 0.f, 0.f};
#pragma unroll
        for (int d = -3; d <= 3; ++d) {
            int tp = t + d;
            if (tp <= 15) acc += kw[d + 3] * w2[tp - 5];
        }
        __builtin_nontemporal_store(acc, (floatx4*)(ob + (size_t)t * ts));
    }
}

extern "C" void kernel_launch(void* const* d_in, const int* in_sizes, int n_in,
                              void* d_out, int out_size, void* d_ws, size_t ws_size,
                              hipStream_t stream) {
    const float* x   = (const float*)d_in[0];
    const float* W1  = (const float*)d_in[1];
    const float* W2  = (const float*)d_in[2];
    const float* Wl1 = (const float*)d_in[3];
    const float* Wl2 = (const float*)d_in[4];
    float* out = (float*)d_out;

    float* pooled = (float*)d_ws;              // B*C*T   = 32768 floats
    float* ty     = pooled + B_ * C_ * T_;     // B*CO*T  =  8192 floats
    float* P      = ty + B_ * CO_ * T_;        // B*C*32  = 65536 floats
    // fp16 transposed copy of x: B*C*T*HW halfs = 12,845,056 B, 8B-aligned
    size_t head_bytes = (size_t)(32768 + 8192 + 65536) * 4;
    _Float16* x16 = (_Float16*)((char*)d_ws + head_bytes);
    size_t need = head_bytes + (size_t)B_ * C_ * T_ * HW_ * sizeof(_Float16);
    bool use16 = (ws_size >= need);

    pool_cvt_kernel<<<B_ * T_ * (C_ / 4), 256, 0, stream>>>(x, pooled, use16 ? x16 : nullptr);
    ty_kernel<<<B_ * CO_, 256, 0, stream>>>(pooled, Wl1, ty);
    abuild_kernel<<<B_ * C_, 64, 0, stream>>>(pooled, ty, W1, W2, Wl2, P);
    if (use16)
        stream16_kernel<<<B_ * C_, 256, 0, stream>>>(x16, P, out);
    else
        stream_kernel<<<B_ * C_, 256, 0, stream>>>(x, P, out);
}

// Round 7
// 68.664 us; speedup vs baseline: 2.7190x; 1.0815x over previous
//
#include <hip/hip_runtime.h>

// Problem constants (from reference setup_inputs)
constexpr int B_  = 8;
constexpr int T_  = 16;
constexpr int C_  = 256;
constexpr int HW_ = 784;   // 28*28
constexpr int CO_ = 64;    // C/4
constexpr int K_  = 7;     // KSZ
constexpr int U2_ = 32;    // 2*T

typedef float floatx4 __attribute__((ext_vector_type(4)));

__device__ __forceinline__ float rfl(float v) {
    return __int_as_float(__builtin_amdgcn_readfirstlane(__float_as_int(v)));
}

// ---------------------------------------------------------------------------
// Kernel 1: adaptive avg pool over (h,w): pooled[b,c,t] = mean(x[b,t,c,:,:])
// One wave per (b,t,c) slice of 784 contiguous floats. 4 waves per block.
// ---------------------------------------------------------------------------
__global__ __launch_bounds__(256) void pool_kernel(const float* __restrict__ x,
                                                   float* __restrict__ pooled) {
    int bid  = blockIdx.x;          // (b*T + t)*(C/4) + cg
    int cg   = bid & 63;
    int bt   = bid >> 6;            // b*T + t
    int t    = bt & 15;
    int b    = bt >> 4;
    int wave = threadIdx.x >> 6;
    int lane = threadIdx.x & 63;
    int c    = cg * 4 + wave;

    const floatx4* p4 = (const floatx4*)(x + ((size_t)bt * C_ + c) * HW_);
    float s = 0.f;
    for (int j = lane; j < 196; j += 64) {   // 196 float4 = 784 floats
        floatx4 v = p4[j];
        s += (v.x + v.y) + (v.z + v.w);
    }
#pragma unroll
    for (int m = 32; m >= 1; m >>= 1) s += __shfl_xor(s, m, 64);
    if (lane == 0) pooled[((size_t)b * C_ + c) * T_ + t] = s * (1.0f / 784.0f);
}

// ---------------------------------------------------------------------------
// Kernel 2: L-branch conv1d (C -> C/4, k=7, pad=3) + tanh
// ty[b,o,t] = tanh( sum_{i,k} pooled[b,i,t+k-3] * Wl1[o,i,k] )
// One block per (b,o); 256 threads = 16 t-groups x 16 i-splitters.
// ---------------------------------------------------------------------------
__global__ __launch_bounds__(256) void ty_kernel(const float* __restrict__ pooled,
                                                 const float* __restrict__ Wl1,
                                                 float* __restrict__ ty) {
    int b = blockIdx.x / CO_;
    int o = blockIdx.x % CO_;
    __shared__ float pld[T_ * 257];   // pld[t*257 + i], padded pitch

    int tid = threadIdx.x;
    for (int idx = tid; idx < C_ * T_; idx += 256) {
        int i  = idx >> 4;
        int tt = idx & 15;
        pld[tt * 257 + i] = pooled[((size_t)b * C_ + i) * T_ + tt];
    }
    __syncthreads();

    int t = tid >> 4;   // 0..15
    int q = tid & 15;   // i-split
    const float* wrow = Wl1 + (size_t)o * (C_ * K_);
    float acc = 0.f;
    for (int j = 0; j < 16; ++j) {
        int i = j * 16 + q;
        const float* wp = wrow + i * K_;
#pragma unroll
        for (int k = 0; k < K_; ++k) {
            int tt = t + k - 3;
            if (tt >= 0 && tt < T_) acc += wp[k] * pld[tt * 257 + i];
        }
    }
    acc += __shfl_xor(acc, 1, 64);
    acc += __shfl_xor(acc, 2, 64);
    acc += __shfl_xor(acc, 4, 64);
    acc += __shfl_xor(acc, 8, 64);
    if (q == 0) ty[((size_t)b * CO_ + o) * T_ + t] = tanhf(acc);
}

// ---------------------------------------------------------------------------
// Kernel 3: fused coefficients + stream. One block per (b,c).
//   Phase A: issue the 11-deep x window prefetch (independent of coefs).
//   Phase B (hidden under A's latency):
//     loc[t] = sigmoid(Wl2[c,:] . ty[b,:,t])
//     kw[k]  = softmax_k( W2 . tanh(W1 . pooled[b,c,:]) )
//   Phase C: y[t'] = loc[t']*x[t']; out[t] = sum_d kw[d+3]*y[t+d], nt-stores.
// ---------------------------------------------------------------------------
__global__ __launch_bounds__(256) void stream_coef_kernel(const float* __restrict__ x,
                                                          const float* __restrict__ pooled,
                                                          const float* __restrict__ ty,
                                                          const float* __restrict__ W1,
                                                          const float* __restrict__ W2,
                                                          const float* __restrict__ Wl2,
                                                          float* __restrict__ out) {
    int bc = blockIdx.x;         // block-uniform
    int b  = bc >> 8;
    int c  = bc & 255;
    int tid = threadIdx.x;
    bool active = tid < 196;

    const size_t chan = ((size_t)(b * T_) * C_ + c) * HW_ + (size_t)tid * 4;
    const float* xb = x + chan;
    float*       ob = out + chan;
    const size_t ts = (size_t)C_ * HW_;   // t-stride in floats

    // ---- Phase A: prefetch first 11 x tiles (raw, loc applied later)
    floatx4 w[11];
    if (active) {
#pragma unroll
        for (int tp = 0; tp < 11; ++tp)
            w[tp] = *(const floatx4*)(xb + (size_t)tp * ts);
    }

    // ---- Phase B: coefficients (all 256 threads; loads overlap Phase A)
    __shared__ float loc_s[T_];
    __shared__ float g_s[U2_];
    __shared__ float s_s[8];
    __shared__ float kw_s[8];

    {   // loc: 16 t-groups x 16 o-splitters (4 o each)
        int t = tid >> 4, q = tid & 15;
        float acc = 0.f;
#pragma unroll
        for (int jj = 0; jj < 4; ++jj) {
            int o = q + jj * 16;
            acc += Wl2[(size_t)c * CO_ + o] * ty[((size_t)b * CO_ + o) * T_ + t];
        }
        acc += __shfl_xor(acc, 1, 64);
        acc += __shfl_xor(acc, 2, 64);
        acc += __shfl_xor(acc, 4, 64);
        acc += __shfl_xor(acc, 8, 64);
        if (q == 0) loc_s[t] = 1.0f / (1.0f + __expf(-acc));
    }
    if (tid < U2_) {
        float acc = 0.f;
#pragma unroll
        for (int t2 = 0; t2 < T_; ++t2)
            acc += pooled[(size_t)bc * T_ + t2] * W1[tid * T_ + t2];
        g_s[tid] = tanhf(acc);
    }
    __syncthreads();
    if (tid < K_) {
        float acc = 0.f;
#pragma unroll
        for (int u = 0; u < U2_; ++u) acc += g_s[u] * W2[tid * U2_ + u];
        s_s[tid] = acc;
    }
    __syncthreads();
    if (tid == 0) {
        float m = s_s[0];
#pragma unroll
        for (int k = 1; k < K_; ++k) m = fmaxf(m, s_s[k]);
        float e[K_], sum = 0.f;
#pragma unroll
        for (int k = 0; k < K_; ++k) { e[k] = __expf(s_s[k] - m); sum += e[k]; }
        float inv = 1.0f / sum;
#pragma unroll
        for (int k = 0; k < K_; ++k) kw_s[k] = e[k] * inv;
    }
    __syncthreads();

    // uniform coefficients -> SGPR
    float kw[K_], lc[T_];
#pragma unroll
    for (int k = 0; k < K_; ++k) kw[k] = rfl(kw_s[k]);
#pragma unroll
    for (int t = 0; t < T_; ++t) lc[t] = rfl(loc_s[t]);

    if (!active) return;

    // ---- Phase C: gate, conv, store
#pragma unroll
    for (int tp = 0; tp < 11; ++tp) w[tp] *= lc[tp];

#pragma unroll
    for (int t = 0; t < 8; ++t) {
        floatx4 acc = {0.f, 0.f, 0.f, 0.f};
#pragma unroll
        for (int d = -3; d <= 3; ++d) {
            int tp = t + d;
            if (tp >= 0 && tp <= 10) acc += kw[d + 3] * w[tp];
        }
        __builtin_nontemporal_store(acc, (floatx4*)(ob + (size_t)t * ts));
    }

    // shift window: w[0..5] = y[5..10]; load y[11..15] into w[6..10]
#pragma unroll
    for (int j = 0; j < 6; ++j) w[j] = w[5 + j];
#pragma unroll
    for (int tp = 11; tp < 16; ++tp)
        w[tp - 5] = *(const floatx4*)(xb + (size_t)tp * ts) * lc[tp];

#pragma unroll
    for (int t = 8; t < 16; ++t) {
        floatx4 acc = {0.f, 0.f, 0.f, 0.f};
#pragma unroll
        for (int d = -3; d <= 3; ++d) {
            int tp = t + d;                 // clipped to [5,15]
            if (tp <= 15) acc += kw[d + 3] * w[tp - 5];
        }
        __builtin_nontemporal_store(acc, (floatx4*)(ob + (size_t)t * ts));
    }
}

extern "C" void kernel_launch(void* const* d_in, const int* in_sizes, int n_in,
                              void* d_out, int out_size, void* d_ws, size_t ws_size,
                              hipStream_t stream) {
    const float* x   = (const float*)d_in[0];
    const float* W1  = (const float*)d_in[1];
    const float* W2  = (const float*)d_in[2];
    const float* Wl1 = (const float*)d_in[3];
    const float* Wl2 = (const float*)d_in[4];
    float* out = (float*)d_out;

    float* pooled = (float*)d_ws;              // B*C*T   = 32768 floats
    float* ty     = pooled + B_ * C_ * T_;     // B*CO*T  =  8192 floats

    pool_kernel<<<B_ * T_ * (C_ / 4), 256, 0, stream>>>(x, pooled);
    ty_kernel<<<B_ * CO_, 256, 0, stream>>>(pooled, Wl1, ty);
    stream_coef_kernel<<<B_ * C_, 256, 0, stream>>>(x, pooled, ty, W1, W2, Wl2, out);
}